// Round 14
// baseline (225.338 us; speedup 1.0000x reference)
//
#include <hip/hip_runtime.h>

// CGCConv: out = (scatter_add(ew*pr[src]*x[src], dst) + x) @ W.T + b
// N=50000, E=800000, D=96, fp32.
//
// Session 2 / Round 13: RESUBMISSION of R9 widened diagnostic (timeouts
// R9-R12). Three structurally different pipelines all measured 141.0-142.6
// => suspect fixed-overhead floor (45us ws re-poison fills in the timed
// window). k_pull body x5 AND k_gemm acc-loop x5; reps kept live via
// asm-volatile sinks + per-rep opaque zero offsets; final rep computes
// bit-identical values => correctness unchanged.
// Read: dur>=230 -> pull/gemm real costs; dur 150-180 -> harness floor.
// pull-x5 row in top-5 gives T_pull; T_gemm = (dur-141.3-4T_pull)/4.
// Base = R1 structure (141.3us best).
// Pipeline: memset(cur1) -> prep(bin) -> sortB(sort|cvt|Wfrag) -> pull -> gemm.

constexpr int NN = 50000;
constexpr int NE = 800000;
constexpr int DD = 96;
constexpr int NB = 196;                       // buckets: dst>>8 (256 nodes)
constexpr int CAPB = 4608;                    // mu=4082 + 8 sigma
constexpr int EPB = 4096;                     // edges per binA block
constexpr int NBLK = (NE + EPB - 1) / EPB;    // 196
constexpr int NCVT = (NN * DD / 4 + 511) / 512;  // 2344 cvt blocks

using s8v = __attribute__((ext_vector_type(8))) short;   // 8 bf16
using f4v = __attribute__((ext_vector_type(4))) float;   // 4 fp32

__device__ inline unsigned short f2bf(float f) {    // RNE fp32->bf16
    unsigned u = __float_as_uint(f);
    return (unsigned short)((u + 0x7FFFu + ((u >> 16) & 1u)) >> 16);
}
__device__ inline float bfh(unsigned short v) {
    return __uint_as_float((unsigned)v << 16);
}
__device__ inline unsigned long long pack_e(int meta, float c) {
    return (unsigned long long)(unsigned)meta |
           ((unsigned long long)(unsigned)__float_as_uint(c) << 32);
}

// Bin 4096 edges -> LDS counting-sort by bucket -> coalesced run writes.
// Entry u64 = {src:16 | dloc:8 | bucket:8 | coef_f32:32}.
__global__ __launch_bounds__(512) void k_prep(const int* __restrict__ src,
                                              const int* __restrict__ dst,
                                              const float* __restrict__ ew,
                                              const float* __restrict__ pr,
                                              int* __restrict__ cur1,
                                              unsigned long long* __restrict__ stage) {
    int tid = threadIdx.x;
    __shared__ int h[256];
    __shared__ int gb[256];
    __shared__ int sc[256];
    __shared__ unsigned long long sorted[EPB];   // 32 KB
    for (int i = tid; i < 256; i += 512) h[i] = 0;
    __syncthreads();
    int base = blockIdx.x * EPB;
    int n = min(EPB, NE - base);

    unsigned long long ent[8]; int bkt[8]; int lrk[8];
    #pragma unroll
    for (int j = 0; j < 8; j++) {
        int e = base + j * 512 + tid;
        bkt[j] = -1;
        if (e < NE) {
            int d = dst[e];
            int s = src[e];
            float c = ew[e] * pr[s];
            int bk = d >> 8;
            bkt[j] = bk;
            lrk[j] = atomicAdd(&h[bk], 1);
            ent[j] = pack_e(s | ((d & 255) << 16) | (bk << 24), c);
        }
    }
    __syncthreads();
    if (tid < 256) sc[tid] = h[tid];
    __syncthreads();
    #pragma unroll
    for (int o = 1; o < 256; o <<= 1) {
        int t = 0;
        if (tid < 256 && tid >= o) t = sc[tid - o];
        __syncthreads();
        if (tid < 256) sc[tid] += t;             // inclusive scan
        __syncthreads();
    }
    for (int i = tid; i < NB; i += 512)
        gb[i] = h[i] ? atomicAdd(&cur1[i], h[i]) : 0;
    __syncthreads();
    #pragma unroll
    for (int j = 0; j < 8; j++)
        if (bkt[j] >= 0)
            sorted[sc[bkt[j]] - h[bkt[j]] + lrk[j]] = ent[j];
    __syncthreads();
    for (int i = tid; i < n; i += 512) {         // coalesced run writes
        unsigned long long e = sorted[i];
        int bk = ((int)(e >> 24)) & 0xff;
        stage[(size_t)bk * CAPB + gb[bk] + (i - (sc[bk] - h[bk]))] = e;
    }
}

// Blocks [0,NB): per-bucket counting sort by dloc; emits u32
// {src | coef_bf16<<16} into the first half of the block's own region.
// Blocks [NB, NB+NCVT): y16 = bf16(x) streaming cvt.
// Block NB+NCVT: W -> bf16 pre-swizzled MFMA fragments (for k_gemm).
__global__ __launch_bounds__(512) void k_sortB(unsigned long long* __restrict__ stage,
                                               const int* __restrict__ cur1,
                                               int* __restrict__ offs,
                                               int* __restrict__ counts,
                                               const float4* __restrict__ x4,
                                               ushort4* __restrict__ y16v,
                                               const float* __restrict__ W,
                                               unsigned short* __restrict__ wfrag) {
    int tid = threadIdx.x;
    int blk = blockIdx.x;
    if (blk >= NB) {
        int ci = blk - NB;
        if (ci < NCVT) {                        // cvt phase
            int i = ci * 512 + tid;
            if (i < NN * DD / 4) {
                float4 v = x4[i];
                y16v[i] = make_ushort4(f2bf(v.x), f2bf(v.y), f2bf(v.z), f2bf(v.w));
            }
        } else {                                // W fragment phase (1 block)
            for (int i = tid; i < 18 * 512; i += 512) {
                int f = i >> 9, r = i & 511;
                int lane = r >> 3, j = r & 7;
                int ks = f / 6, nt = f - 6 * ks;
                int n = nt * 16 + (lane & 15);
                int k = ks * 32 + (lane >> 4) * 8 + j;
                wfrag[i] = f2bf(W[n * DD + k]);
            }
        }
        return;
    }
    __shared__ int h[256];
    __shared__ int sc[256];
    __shared__ unsigned sorted[CAPB];            // u32, 18.4 KB
    size_t base = (size_t)blk * CAPB;
    int n = cur1[blk];

    for (int i = tid; i < 256; i += 512) h[i] = 0;
    __syncthreads();

    unsigned e32[9]; int dl[9]; int lrk[9];
    int m = 0;
    for (int i = tid; i < n; i += 512) {
        unsigned long long e = stage[base + i];
        int dloc = ((int)(e >> 16)) & 0xff;
        unsigned cb = (unsigned)(e >> 32);       // coef fp32 bits
        unsigned cbf = (cb + 0x7FFFu + ((cb >> 16) & 1u)) >> 16;  // bf16
        e32[m] = ((unsigned)e & 0xffffu) | (cbf << 16);
        dl[m] = dloc;
        lrk[m] = atomicAdd(&h[dloc], 1);
        m++;
    }
    __syncthreads();
    if (tid < 256) sc[tid] = h[tid];
    __syncthreads();
    #pragma unroll
    for (int o = 1; o < 256; o <<= 1) {
        int t = 0;
        if (tid < 256 && tid >= o) t = sc[tid - o];
        __syncthreads();
        if (tid < 256) sc[tid] += t;             // inclusive
        __syncthreads();
    }
    m = 0;
    for (int i = tid; i < n; i += 512) {
        sorted[sc[dl[m]] - h[dl[m]] + lrk[m]] = e32[m];
        m++;
    }
    __syncthreads();
    unsigned* outp = (unsigned*)(stage + base);  // first half of own region
    for (int i = tid; i < n; i += 512) outp[i] = sorted[i];
    if (tid < 256) {
        int d = (blk << 8) + tid;
        if (d < NN) {
            offs[d] = (int)(2 * base) + sc[tid] - h[tid];   // u32 index
            counts[d] = h[tid];
        }
    }
}

// Pull-aggregate: 8 nodes/block, 32 lanes/node, lanes 0..23 own one ushort4.
// DIAGNOSTIC x5: body repeated 5x; reps sunk via asm volatile, final rep's
// values (computed with runtime-zero offset) are the real result.
__global__ __launch_bounds__(256) void k_pull(const ushort4* __restrict__ y16v,
                                              const float4* __restrict__ x4,
                                              const int* __restrict__ offs,
                                              const int* __restrict__ counts,
                                              const unsigned* __restrict__ ep,
                                              ushort4* __restrict__ io16v) {
    int g = blockIdx.x * 8 + (threadIdx.x >> 5);
    int lane = threadIdx.x & 31;
    if (g >= NN || lane >= 24) return;
    int beg0 = offs[g];
    int deg = counts[g];
    float ax, ay, az, aw;
    #pragma unroll 1
    for (int rep = 0; rep < 5; rep++) {
        unsigned zr;                             // opaque 0, fresh per rep:
        asm volatile("v_mov_b32 %0, 0" : "=v"(zr));  // defeats CSE across reps
        int beg = beg0 + (int)zr;
        ax = 0.f; ay = 0.f; az = 0.f; aw = 0.f;
        int k = 0;
        for (; k + 8 <= deg; k += 8) {
            unsigned e[8];
            #pragma unroll
            for (int j = 0; j < 8; j++) e[j] = ep[beg + k + j];
            ushort4 u[8];
            #pragma unroll
            for (int j = 0; j < 8; j++)
                u[j] = y16v[(size_t)(e[j] & 0xffff) * 24 + lane];
            #pragma unroll
            for (int j = 0; j < 8; j++) {
                float c = bfh((unsigned short)(e[j] >> 16));
                ax += c * bfh(u[j].x);
                ay += c * bfh(u[j].y);
                az += c * bfh(u[j].z);
                aw += c * bfh(u[j].w);
            }
        }
        for (; k + 4 <= deg; k += 4) {
            unsigned e[4];
            #pragma unroll
            for (int j = 0; j < 4; j++) e[j] = ep[beg + k + j];
            ushort4 u[4];
            #pragma unroll
            for (int j = 0; j < 4; j++)
                u[j] = y16v[(size_t)(e[j] & 0xffff) * 24 + lane];
            #pragma unroll
            for (int j = 0; j < 4; j++) {
                float c = bfh((unsigned short)(e[j] >> 16));
                ax += c * bfh(u[j].x);
                ay += c * bfh(u[j].y);
                az += c * bfh(u[j].z);
                aw += c * bfh(u[j].w);
            }
        }
        for (; k < deg; k++) {
            unsigned e = ep[beg + k];
            ushort4 u = y16v[(size_t)(e & 0xffff) * 24 + lane];
            float c = bfh((unsigned short)(e >> 16));
            ax += c * bfh(u.x);
            ay += c * bfh(u.y);
            az += c * bfh(u.z);
            aw += c * bfh(u.w);
        }
        asm volatile("" :: "v"(ax), "v"(ay), "v"(az), "v"(aw));  // keep reps live
    }
    float4 xn = x4[(size_t)g * 24 + lane];
    io16v[(size_t)g * 24 + lane] = make_ushort4(f2bf(ax + xn.x), f2bf(ay + xn.y),
                                                f2bf(az + xn.z), f2bf(aw + xn.w));
}

// MFMA GEMM: out[r,o] = sum_d io16[r,d]*W[o,d] + b[o], fp32 out.
// DIAGNOSTIC x5: acc-compute repeated 5x (opaque-zero pointer offset per
// rep; all 6 accs sunk per rep so no MFMA is DCE'd); final rep feeds store.
// C/D: col=lane&15, row=quad*4+reg (HW-verified; absmax-confirmed R11).
__global__ __launch_bounds__(256) void k_gemm(const unsigned short* __restrict__ io16,
                                              const unsigned short* __restrict__ wfrag,
                                              const float* __restrict__ b,
                                              float* __restrict__ out) {
    int tid = threadIdx.x;
    int wave = tid >> 6, lane = tid & 63;
    int quad = lane >> 4, m16 = lane & 15;
    int r0 = blockIdx.x * 64 + wave * 16;
    int rowa = r0 + m16;
    if (rowa >= NN) rowa = NN - 1;           // clamped A read, store masked

    const s8v* wf = (const s8v*)wfrag;       // frag (ks*6+nt) x 64 lanes

    f4v acc[6];
    #pragma unroll 1
    for (int rep = 0; rep < 5; rep++) {
        unsigned zr;                             // opaque 0, fresh per rep
        asm volatile("v_mov_b32 %0, 0" : "=v"(zr));
        const unsigned short* iop = io16 + zr;
        #pragma unroll
        for (int nt = 0; nt < 6; nt++) acc[nt] = (f4v){0.f, 0.f, 0.f, 0.f};
        #pragma unroll
        for (int ks = 0; ks < 3; ks++) {
            s8v a = *(const s8v*)(iop + (size_t)rowa * DD + ks * 32 + quad * 8);
            #pragma unroll
            for (int nt = 0; nt < 6; nt++) {
                s8v bb = wf[(ks * 6 + nt) * 64 + lane];
                acc[nt] = __builtin_amdgcn_mfma_f32_16x16x32_bf16(a, bb, acc[nt], 0, 0, 0);
            }
        }
        asm volatile("" :: "v"(acc[0][0]), "v"(acc[1][0]), "v"(acc[2][0]),
                          "v"(acc[3][0]), "v"(acc[4][0]), "v"(acc[5][0]));
    }

    #pragma unroll
    for (int nt = 0; nt < 6; nt++) {
        float bias = b[nt * 16 + m16];
        #pragma unroll
        for (int reg = 0; reg < 4; reg++) {
            int rr = r0 + quad * 4 + reg;
            if (rr < NN)
                out[(size_t)rr * DD + nt * 16 + m16] = acc[nt][reg] + bias;
        }
    }
}

extern "C" void kernel_launch(void* const* d_in, const int* in_sizes, int n_in,
                              void* d_out, int out_size, void* d_ws, size_t ws_size,
                              hipStream_t stream) {
    const float* x  = (const float*)d_in[0];
    const int*   ei = (const int*)d_in[1];   // [2,E]: [0..E)=src, [E..2E)=dst
    const float* ew = (const float*)d_in[2];
    const float* pr = (const float*)d_in[3];
    const float* W  = (const float*)d_in[4];
    const float* b  = (const float*)d_in[5];
    float* out = (float*)d_out;

    // ws layout (~26.9 MB)
    unsigned long long* stage = (unsigned long long*)d_ws;       // NB*CAPB u64
    unsigned short* y16 = (unsigned short*)(stage + (size_t)NB * CAPB);  // 9.6MB
    int* cur1   = (int*)(y16 + (size_t)NN * DD);      // 196
    int* offs   = cur1 + NB;                          // 50000
    int* counts = offs + NN;                          // 50000
    unsigned short* io16 = (unsigned short*)(counts + NN);       // 9.6MB
    unsigned short* wfrag = io16 + (size_t)NN * DD;   // 18*512 bf16 = 18.4KB

    const int* src = ei;
    const int* dst = ei + NE;

    hipMemsetAsync(cur1, 0, NB * sizeof(int), stream);
    k_prep<<<NBLK, 512, 0, stream>>>(src, dst, ew, pr, cur1, stage);
    k_sortB<<<NB + NCVT + 1, 512, 0, stream>>>(stage, cur1, offs, counts,
                                               (const float4*)x, (ushort4*)y16,
                                               W, wfrag);
    k_pull<<<(NN + 7) / 8, 256, 0, stream>>>((const ushort4*)y16, (const float4*)x,
                                             offs, counts, (const unsigned*)stage,
                                             (ushort4*)io16);
    k_gemm<<<(NN + 63) / 64, 256, 0, stream>>>(io16, wfrag, b, out);
}

// Round 15
// 164.071 us; speedup vs baseline: 1.3734x; 1.3734x over previous
//
#include <hip/hip_runtime.h>

// CGCConv: out = (scatter_add(ew*pr[src]*x[src], dst) + x) @ W.T + b
// N=50000, E=800000, D=96, fp32.
//
// Session 2 / Round 15. R14 diagnostic: pull loop ~21us/rep (VALUBusy 52%,
// Occ 71%, 0 conflicts, ~48MB L2-miss/rep), gemm loop ~0-1us. Accounting:
// prep+sortB ~90-100us = 2/3 of the 141us envelope — the pipeline spends
// most time SORTING edges, not computing.
// CHANGE: kill the entire 2-phase LDS-sort (prep+sortB+stage+scan). Degree
// is Poisson(16), max over 50k nodes ~45 << 64 => fixed-capacity node-major
// layout: one pass, slot=atomicAdd(&cnt[dst],1); ep[dst*64+slot]={src|cbf16}.
// No scan, no stage round-trip, 2 fewer heavy kernels. Pull reads beg=g*64,
// cnt[g] (same gather pattern as before); gemm unchanged (wfrag path).
// Edge order within node changes (atomic vs sorted) — fp32 reorder noise
// << bf16 quantization (absmax 0.0625).
// Pipeline (3 kernels): memset(cnt) -> bin(edges|cvt|Wfrag) -> pull -> gemm.
// Prediction: dur 141 -> ~65-85 if sort was the cost; ~135-140 if envelope
// was fixed overhead (decisive either way).

constexpr int NN = 50000;
constexpr int NE = 800000;
constexpr int DD = 96;
constexpr int CAPN = 64;                      // per-node edge capacity (max deg ~45)
constexpr int NEBLK = (NE + 511) / 512;       // 1563 edge blocks
constexpr int NCVT = (NN * DD / 4 + 511) / 512;  // 2344 cvt blocks

using s8v = __attribute__((ext_vector_type(8))) short;   // 8 bf16
using f4v = __attribute__((ext_vector_type(4))) float;   // 4 fp32

__device__ inline unsigned short f2bf(float f) {    // RNE fp32->bf16
    unsigned u = __float_as_uint(f);
    return (unsigned short)((u + 0x7FFFu + ((u >> 16) & 1u)) >> 16);
}
__device__ inline float bfh(unsigned short v) {
    return __uint_as_float((unsigned)v << 16);
}

// Blocks [0,NEBLK): one edge/thread: coef=ew*pr[src] (fp32->bf16 RNE),
// slot=atomicAdd(cnt[dst]), ep[dst*64+slot] = {src:16 | coef_bf16:16}.
// Blocks [NEBLK, NEBLK+NCVT): y16 = bf16(x) streaming cvt.
// Block NEBLK+NCVT: W -> bf16 pre-swizzled MFMA fragments (for k_gemm).
__global__ __launch_bounds__(512) void k_bin(const int* __restrict__ src,
                                             const int* __restrict__ dst,
                                             const float* __restrict__ ew,
                                             const float* __restrict__ pr,
                                             int* __restrict__ cnt,
                                             unsigned* __restrict__ ep,
                                             const float4* __restrict__ x4,
                                             ushort4* __restrict__ y16v,
                                             const float* __restrict__ W,
                                             unsigned short* __restrict__ wfrag) {
    int tid = threadIdx.x;
    int blk = blockIdx.x;
    if (blk >= NEBLK) {
        int ci = blk - NEBLK;
        if (ci < NCVT) {                        // cvt phase
            int i = ci * 512 + tid;
            if (i < NN * DD / 4) {
                float4 v = x4[i];
                y16v[i] = make_ushort4(f2bf(v.x), f2bf(v.y), f2bf(v.z), f2bf(v.w));
            }
        } else {                                // W fragment phase (1 block)
            for (int i = tid; i < 18 * 512; i += 512) {
                int f = i >> 9, r = i & 511;
                int lane = r >> 3, j = r & 7;
                int ks = f / 6, nt = f - 6 * ks;
                int n = nt * 16 + (lane & 15);
                int k = ks * 32 + (lane >> 4) * 8 + j;
                wfrag[i] = f2bf(W[n * DD + k]);
            }
        }
        return;
    }
    int e = blk * 512 + tid;
    if (e >= NE) return;
    int d = dst[e];
    int s = src[e];
    float c = ew[e] * pr[s];
    unsigned cbf = f2bf(c);
    int slot = atomicAdd(&cnt[d], 1);
    if (slot < CAPN)                            // max deg ~45, never trips
        ep[((size_t)d << 6) + slot] = (unsigned)(s & 0xffff) | (cbf << 16);
}

// Pull-aggregate: 8 nodes/block, 32 lanes/node, lanes 0..23 own one ushort4
// (4 bf16 channels, 8B gather). beg = g*64 (fixed stride). Writes
// io16 = bf16(aggr + x). Inner pattern unchanged from measured R14 kernel.
__global__ __launch_bounds__(256) void k_pull(const ushort4* __restrict__ y16v,
                                              const float4* __restrict__ x4,
                                              const int* __restrict__ cnt,
                                              const unsigned* __restrict__ ep,
                                              ushort4* __restrict__ io16v) {
    int g = blockIdx.x * 8 + (threadIdx.x >> 5);
    int lane = threadIdx.x & 31;
    if (g >= NN || lane >= 24) return;
    int beg = g << 6;
    int deg = cnt[g];
    float ax = 0.f, ay = 0.f, az = 0.f, aw = 0.f;
    int k = 0;
    for (; k + 8 <= deg; k += 8) {
        unsigned e[8];
        #pragma unroll
        for (int j = 0; j < 8; j++) e[j] = ep[beg + k + j];
        ushort4 u[8];
        #pragma unroll
        for (int j = 0; j < 8; j++)
            u[j] = y16v[(size_t)(e[j] & 0xffff) * 24 + lane];
        #pragma unroll
        for (int j = 0; j < 8; j++) {
            float c = bfh((unsigned short)(e[j] >> 16));
            ax += c * bfh(u[j].x);
            ay += c * bfh(u[j].y);
            az += c * bfh(u[j].z);
            aw += c * bfh(u[j].w);
        }
    }
    for (; k + 4 <= deg; k += 4) {
        unsigned e[4];
        #pragma unroll
        for (int j = 0; j < 4; j++) e[j] = ep[beg + k + j];
        ushort4 u[4];
        #pragma unroll
        for (int j = 0; j < 4; j++)
            u[j] = y16v[(size_t)(e[j] & 0xffff) * 24 + lane];
        #pragma unroll
        for (int j = 0; j < 4; j++) {
            float c = bfh((unsigned short)(e[j] >> 16));
            ax += c * bfh(u[j].x);
            ay += c * bfh(u[j].y);
            az += c * bfh(u[j].z);
            aw += c * bfh(u[j].w);
        }
    }
    for (; k < deg; k++) {
        unsigned e = ep[beg + k];
        ushort4 u = y16v[(size_t)(e & 0xffff) * 24 + lane];
        float c = bfh((unsigned short)(e >> 16));
        ax += c * bfh(u.x);
        ay += c * bfh(u.y);
        az += c * bfh(u.z);
        aw += c * bfh(u.w);
    }
    float4 xn = x4[(size_t)g * 24 + lane];
    io16v[(size_t)g * 24 + lane] = make_ushort4(f2bf(ax + xn.x), f2bf(ay + xn.y),
                                                f2bf(az + xn.z), f2bf(aw + xn.w));
}

// MFMA GEMM: out[r,o] = sum_d io16[r,d]*W[o,d] + b[o], fp32 out.
// B-frags pre-swizzled in ws (wfrag), loaded coalesced 16B/lane from L2.
// C/D: col=lane&15, row=quad*4+reg (HW-verified; absmax-confirmed).
__global__ __launch_bounds__(256) void k_gemm(const unsigned short* __restrict__ io16,
                                              const unsigned short* __restrict__ wfrag,
                                              const float* __restrict__ b,
                                              float* __restrict__ out) {
    int tid = threadIdx.x;
    int wave = tid >> 6, lane = tid & 63;
    int quad = lane >> 4, m16 = lane & 15;
    int r0 = blockIdx.x * 64 + wave * 16;
    int rowa = r0 + m16;
    if (rowa >= NN) rowa = NN - 1;           // clamped A read, store masked

    const s8v* wf = (const s8v*)wfrag;       // frag (ks*6+nt) x 64 lanes

    f4v acc[6];
    #pragma unroll
    for (int nt = 0; nt < 6; nt++) acc[nt] = (f4v){0.f, 0.f, 0.f, 0.f};

    #pragma unroll
    for (int ks = 0; ks < 3; ks++) {
        s8v a = *(const s8v*)(io16 + (size_t)rowa * DD + ks * 32 + quad * 8);
        #pragma unroll
        for (int nt = 0; nt < 6; nt++) {
            s8v bb = wf[(ks * 6 + nt) * 64 + lane];
            acc[nt] = __builtin_amdgcn_mfma_f32_16x16x32_bf16(a, bb, acc[nt], 0, 0, 0);
        }
    }

    #pragma unroll
    for (int nt = 0; nt < 6; nt++) {
        float bias = b[nt * 16 + m16];
        #pragma unroll
        for (int reg = 0; reg < 4; reg++) {
            int rr = r0 + quad * 4 + reg;
            if (rr < NN)
                out[(size_t)rr * DD + nt * 16 + m16] = acc[nt][reg] + bias;
        }
    }
}

extern "C" void kernel_launch(void* const* d_in, const int* in_sizes, int n_in,
                              void* d_out, int out_size, void* d_ws, size_t ws_size,
                              hipStream_t stream) {
    const float* x  = (const float*)d_in[0];
    const int*   ei = (const int*)d_in[1];   // [2,E]: [0..E)=src, [E..2E)=dst
    const float* ew = (const float*)d_in[2];
    const float* pr = (const float*)d_in[3];
    const float* W  = (const float*)d_in[4];
    const float* b  = (const float*)d_in[5];
    float* out = (float*)d_out;

    // ws layout (~32.2 MB)
    unsigned* ep = (unsigned*)d_ws;                          // NN*64 u32 = 12.8MB
    unsigned short* y16 = (unsigned short*)(ep + (size_t)NN * CAPN);  // 9.6MB
    int* cnt = (int*)(y16 + (size_t)NN * DD);                // 200KB
    unsigned short* io16 = (unsigned short*)(cnt + NN);      // 9.6MB
    unsigned short* wfrag = io16 + (size_t)NN * DD;          // 18.4KB

    const int* src = ei;
    const int* dst = ei + NE;

    hipMemsetAsync(cnt, 0, NN * sizeof(int), stream);
    k_bin<<<NEBLK + NCVT + 1, 512, 0, stream>>>(src, dst, ew, pr, cnt, ep,
                                                (const float4*)x, (ushort4*)y16,
                                                W, wfrag);
    k_pull<<<(NN + 7) / 8, 256, 0, stream>>>((const ushort4*)y16, (const float4*)x,
                                             cnt, ep, (ushort4*)io16);
    k_gemm<<<(NN + 63) / 64, 256, 0, stream>>>(io16, wfrag, b, out);
}

// Round 17
// 138.550 us; speedup vs baseline: 1.6264x; 1.1842x over previous
//
#include <hip/hip_runtime.h>

// CGCConv: out = (scatter_add(ew*pr[src]*x[src], dst) + x) @ W.T + b
// N=50000, E=800000, D=96, fp32.
//
// Session 2 / Round 17: RESUBMISSION of R16 (broker timeout, never ran).
// R15 lessons: (a) one-pass atomic bin = 59us, op-throughput-limited —
// REVERTED to R1 two-phase sort (prep+sortB = 36us by algebra).
// (b) Fixed overhead F ~65-70us (256MiB ws re-poison ~45us in-window +
// memset + gaps); baseline kernel time only ~72us (sort 36, pull 28, gemm 8).
// CHANGE (one lever): k_pull gather 24 lanes x 8B -> 12 lanes x 16B
// (ushort8). Same bytes, HALF the memory ops + address VALU (R14 showed
// VALUBusy 52% => op-bound component). Same per-channel sum order =>
// absmax bit-identical. prep/sortB/gemm = verified R1 code (controls).
// Prediction: pull 28 -> ~19-22, dur 141.3 -> ~132-136.
// Pipeline: memset(cur1) -> prep(bin) -> sortB(sort|cvt|Wfrag) -> pull -> gemm.

constexpr int NN = 50000;
constexpr int NE = 800000;
constexpr int DD = 96;
constexpr int NB = 196;                       // buckets: dst>>8 (256 nodes)
constexpr int CAPB = 4608;                    // mu=4082 + 8 sigma
constexpr int EPB = 4096;                     // edges per binA block
constexpr int NBLK = (NE + EPB - 1) / EPB;    // 196
constexpr int NCVT = (NN * DD / 4 + 511) / 512;  // 2344 cvt blocks

using s8v = __attribute__((ext_vector_type(8))) short;   // 8 bf16
using f4v = __attribute__((ext_vector_type(4))) float;   // 4 fp32
using u16x8 = __attribute__((ext_vector_type(8))) unsigned short;  // 16B

__device__ inline unsigned short f2bf(float f) {    // RNE fp32->bf16
    unsigned u = __float_as_uint(f);
    return (unsigned short)((u + 0x7FFFu + ((u >> 16) & 1u)) >> 16);
}
__device__ inline float bfh(unsigned short v) {
    return __uint_as_float((unsigned)v << 16);
}
__device__ inline unsigned long long pack_e(int meta, float c) {
    return (unsigned long long)(unsigned)meta |
           ((unsigned long long)(unsigned)__float_as_uint(c) << 32);
}

// Bin 4096 edges -> LDS counting-sort by bucket -> coalesced run writes.
// Entry u64 = {src:16 | dloc:8 | bucket:8 | coef_f32:32}.
__global__ __launch_bounds__(512) void k_prep(const int* __restrict__ src,
                                              const int* __restrict__ dst,
                                              const float* __restrict__ ew,
                                              const float* __restrict__ pr,
                                              int* __restrict__ cur1,
                                              unsigned long long* __restrict__ stage) {
    int tid = threadIdx.x;
    __shared__ int h[256];
    __shared__ int gb[256];
    __shared__ int sc[256];
    __shared__ unsigned long long sorted[EPB];   // 32 KB
    for (int i = tid; i < 256; i += 512) h[i] = 0;
    __syncthreads();
    int base = blockIdx.x * EPB;
    int n = min(EPB, NE - base);

    unsigned long long ent[8]; int bkt[8]; int lrk[8];
    #pragma unroll
    for (int j = 0; j < 8; j++) {
        int e = base + j * 512 + tid;
        bkt[j] = -1;
        if (e < NE) {
            int d = dst[e];
            int s = src[e];
            float c = ew[e] * pr[s];
            int bk = d >> 8;
            bkt[j] = bk;
            lrk[j] = atomicAdd(&h[bk], 1);
            ent[j] = pack_e(s | ((d & 255) << 16) | (bk << 24), c);
        }
    }
    __syncthreads();
    if (tid < 256) sc[tid] = h[tid];
    __syncthreads();
    #pragma unroll
    for (int o = 1; o < 256; o <<= 1) {
        int t = 0;
        if (tid < 256 && tid >= o) t = sc[tid - o];
        __syncthreads();
        if (tid < 256) sc[tid] += t;             // inclusive scan
        __syncthreads();
    }
    for (int i = tid; i < NB; i += 512)
        gb[i] = h[i] ? atomicAdd(&cur1[i], h[i]) : 0;
    __syncthreads();
    #pragma unroll
    for (int j = 0; j < 8; j++)
        if (bkt[j] >= 0)
            sorted[sc[bkt[j]] - h[bkt[j]] + lrk[j]] = ent[j];
    __syncthreads();
    for (int i = tid; i < n; i += 512) {         // coalesced run writes
        unsigned long long e = sorted[i];
        int bk = ((int)(e >> 24)) & 0xff;
        stage[(size_t)bk * CAPB + gb[bk] + (i - (sc[bk] - h[bk]))] = e;
    }
}

// Blocks [0,NB): per-bucket counting sort by dloc; emits u32
// {src | coef_bf16<<16} into the first half of the block's own region.
// Blocks [NB, NB+NCVT): y16 = bf16(x) streaming cvt.
// Block NB+NCVT: W -> bf16 pre-swizzled MFMA fragments (for k_gemm).
__global__ __launch_bounds__(512) void k_sortB(unsigned long long* __restrict__ stage,
                                               const int* __restrict__ cur1,
                                               int* __restrict__ offs,
                                               int* __restrict__ counts,
                                               const float4* __restrict__ x4,
                                               ushort4* __restrict__ y16v,
                                               const float* __restrict__ W,
                                               unsigned short* __restrict__ wfrag) {
    int tid = threadIdx.x;
    int blk = blockIdx.x;
    if (blk >= NB) {
        int ci = blk - NB;
        if (ci < NCVT) {                        // cvt phase
            int i = ci * 512 + tid;
            if (i < NN * DD / 4) {
                float4 v = x4[i];
                y16v[i] = make_ushort4(f2bf(v.x), f2bf(v.y), f2bf(v.z), f2bf(v.w));
            }
        } else {                                // W fragment phase (1 block)
            for (int i = tid; i < 18 * 512; i += 512) {
                int f = i >> 9, r = i & 511;
                int lane = r >> 3, j = r & 7;
                int ks = f / 6, nt = f - 6 * ks;
                int n = nt * 16 + (lane & 15);
                int k = ks * 32 + (lane >> 4) * 8 + j;
                wfrag[i] = f2bf(W[n * DD + k]);
            }
        }
        return;
    }
    __shared__ int h[256];
    __shared__ int sc[256];
    __shared__ unsigned sorted[CAPB];            // u32, 18.4 KB
    size_t base = (size_t)blk * CAPB;
    int n = cur1[blk];

    for (int i = tid; i < 256; i += 512) h[i] = 0;
    __syncthreads();

    unsigned e32[9]; int dl[9]; int lrk[9];
    int m = 0;
    for (int i = tid; i < n; i += 512) {
        unsigned long long e = stage[base + i];
        int dloc = ((int)(e >> 16)) & 0xff;
        unsigned cb = (unsigned)(e >> 32);       // coef fp32 bits
        unsigned cbf = (cb + 0x7FFFu + ((cb >> 16) & 1u)) >> 16;  // bf16
        e32[m] = ((unsigned)e & 0xffffu) | (cbf << 16);
        dl[m] = dloc;
        lrk[m] = atomicAdd(&h[dloc], 1);
        m++;
    }
    __syncthreads();
    if (tid < 256) sc[tid] = h[tid];
    __syncthreads();
    #pragma unroll
    for (int o = 1; o < 256; o <<= 1) {
        int t = 0;
        if (tid < 256 && tid >= o) t = sc[tid - o];
        __syncthreads();
        if (tid < 256) sc[tid] += t;             // inclusive
        __syncthreads();
    }
    m = 0;
    for (int i = tid; i < n; i += 512) {
        sorted[sc[dl[m]] - h[dl[m]] + lrk[m]] = e32[m];
        m++;
    }
    __syncthreads();
    unsigned* outp = (unsigned*)(stage + base);  // first half of own region
    for (int i = tid; i < n; i += 512) outp[i] = sorted[i];
    if (tid < 256) {
        int d = (blk << 8) + tid;
        if (d < NN) {
            offs[d] = (int)(2 * base) + sc[tid] - h[tid];   // u32 index
            counts[d] = h[tid];
        }
    }
}

// Pull-aggregate: 8 nodes/block, 32 lanes/node, lanes 0..11 own one ushort8
// (8 bf16 channels, 16B gather — half the memory ops of the 24x8B layout).
// Writes io16 = bf16(aggr + x). Same per-channel sum order as before.
__global__ __launch_bounds__(256) void k_pull(const u16x8* __restrict__ y16v8,
                                              const float4* __restrict__ x4,
                                              const int* __restrict__ offs,
                                              const int* __restrict__ counts,
                                              const unsigned* __restrict__ ep,
                                              u16x8* __restrict__ io16v8) {
    int g = blockIdx.x * 8 + (threadIdx.x >> 5);
    int lane = threadIdx.x & 31;
    if (g >= NN || lane >= 12) return;
    int beg = offs[g];
    int deg = counts[g];
    float a0 = 0.f, a1 = 0.f, a2 = 0.f, a3 = 0.f;
    float a4 = 0.f, a5 = 0.f, a6 = 0.f, a7 = 0.f;
    int k = 0;
    for (; k + 8 <= deg; k += 8) {
        unsigned e[8];
        #pragma unroll
        for (int j = 0; j < 8; j++) e[j] = ep[beg + k + j];
        u16x8 u[8];
        #pragma unroll
        for (int j = 0; j < 8; j++)
            u[j] = y16v8[(size_t)(e[j] & 0xffff) * 12 + lane];
        #pragma unroll
        for (int j = 0; j < 8; j++) {
            float c = bfh((unsigned short)(e[j] >> 16));
            a0 += c * bfh(u[j][0]); a1 += c * bfh(u[j][1]);
            a2 += c * bfh(u[j][2]); a3 += c * bfh(u[j][3]);
            a4 += c * bfh(u[j][4]); a5 += c * bfh(u[j][5]);
            a6 += c * bfh(u[j][6]); a7 += c * bfh(u[j][7]);
        }
    }
    for (; k + 4 <= deg; k += 4) {
        unsigned e[4];
        #pragma unroll
        for (int j = 0; j < 4; j++) e[j] = ep[beg + k + j];
        u16x8 u[4];
        #pragma unroll
        for (int j = 0; j < 4; j++)
            u[j] = y16v8[(size_t)(e[j] & 0xffff) * 12 + lane];
        #pragma unroll
        for (int j = 0; j < 4; j++) {
            float c = bfh((unsigned short)(e[j] >> 16));
            a0 += c * bfh(u[j][0]); a1 += c * bfh(u[j][1]);
            a2 += c * bfh(u[j][2]); a3 += c * bfh(u[j][3]);
            a4 += c * bfh(u[j][4]); a5 += c * bfh(u[j][5]);
            a6 += c * bfh(u[j][6]); a7 += c * bfh(u[j][7]);
        }
    }
    for (; k < deg; k++) {
        unsigned e = ep[beg + k];
        u16x8 u = y16v8[(size_t)(e & 0xffff) * 12 + lane];
        float c = bfh((unsigned short)(e >> 16));
        a0 += c * bfh(u[0]); a1 += c * bfh(u[1]);
        a2 += c * bfh(u[2]); a3 += c * bfh(u[3]);
        a4 += c * bfh(u[4]); a5 += c * bfh(u[5]);
        a6 += c * bfh(u[6]); a7 += c * bfh(u[7]);
    }
    float4 xl = x4[(size_t)g * 24 + lane * 2];
    float4 xh = x4[(size_t)g * 24 + lane * 2 + 1];
    u16x8 o;
    o[0] = f2bf(a0 + xl.x); o[1] = f2bf(a1 + xl.y);
    o[2] = f2bf(a2 + xl.z); o[3] = f2bf(a3 + xl.w);
    o[4] = f2bf(a4 + xh.x); o[5] = f2bf(a5 + xh.y);
    o[6] = f2bf(a6 + xh.z); o[7] = f2bf(a7 + xh.w);
    io16v8[(size_t)g * 12 + lane] = o;
}

// MFMA GEMM: out[r,o] = sum_d io16[r,d]*W[o,d] + b[o], fp32 out.
// B-frags pre-swizzled in ws (wfrag), loaded coalesced 16B/lane from L2.
// C/D: col=lane&15, row=quad*4+reg (HW-verified; absmax-confirmed).
__global__ __launch_bounds__(256) void k_gemm(const unsigned short* __restrict__ io16,
                                              const unsigned short* __restrict__ wfrag,
                                              const float* __restrict__ b,
                                              float* __restrict__ out) {
    int tid = threadIdx.x;
    int wave = tid >> 6, lane = tid & 63;
    int quad = lane >> 4, m16 = lane & 15;
    int r0 = blockIdx.x * 64 + wave * 16;
    int rowa = r0 + m16;
    if (rowa >= NN) rowa = NN - 1;           // clamped A read, store masked

    const s8v* wf = (const s8v*)wfrag;       // frag (ks*6+nt) x 64 lanes

    f4v acc[6];
    #pragma unroll
    for (int nt = 0; nt < 6; nt++) acc[nt] = (f4v){0.f, 0.f, 0.f, 0.f};

    #pragma unroll
    for (int ks = 0; ks < 3; ks++) {
        s8v a = *(const s8v*)(io16 + (size_t)rowa * DD + ks * 32 + quad * 8);
        #pragma unroll
        for (int nt = 0; nt < 6; nt++) {
            s8v bb = wf[(ks * 6 + nt) * 64 + lane];
            acc[nt] = __builtin_amdgcn_mfma_f32_16x16x32_bf16(a, bb, acc[nt], 0, 0, 0);
        }
    }

    #pragma unroll
    for (int nt = 0; nt < 6; nt++) {
        float bias = b[nt * 16 + m16];
        #pragma unroll
        for (int reg = 0; reg < 4; reg++) {
            int rr = r0 + quad * 4 + reg;
            if (rr < NN)
                out[(size_t)rr * DD + nt * 16 + m16] = acc[nt][reg] + bias;
        }
    }
}

extern "C" void kernel_launch(void* const* d_in, const int* in_sizes, int n_in,
                              void* d_out, int out_size, void* d_ws, size_t ws_size,
                              hipStream_t stream) {
    const float* x  = (const float*)d_in[0];
    const int*   ei = (const int*)d_in[1];   // [2,E]: [0..E)=src, [E..2E)=dst
    const float* ew = (const float*)d_in[2];
    const float* pr = (const float*)d_in[3];
    const float* W  = (const float*)d_in[4];
    const float* b  = (const float*)d_in[5];
    float* out = (float*)d_out;

    // ws layout (~26.9 MB)
    unsigned long long* stage = (unsigned long long*)d_ws;       // NB*CAPB u64
    unsigned short* y16 = (unsigned short*)(stage + (size_t)NB * CAPB);  // 9.6MB
    int* cur1   = (int*)(y16 + (size_t)NN * DD);      // 196
    int* offs   = cur1 + NB;                          // 50000
    int* counts = offs + NN;                          // 50000
    unsigned short* io16 = (unsigned short*)(counts + NN);       // 9.6MB
    unsigned short* wfrag = io16 + (size_t)NN * DD;   // 18*512 bf16 = 18.4KB

    const int* src = ei;
    const int* dst = ei + NE;

    hipMemsetAsync(cur1, 0, NB * sizeof(int), stream);
    k_prep<<<NBLK, 512, 0, stream>>>(src, dst, ew, pr, cur1, stage);
    k_sortB<<<NB + NCVT + 1, 512, 0, stream>>>(stage, cur1, offs, counts,
                                               (const float4*)x, (ushort4*)y16,
                                               W, wfrag);
    k_pull<<<(NN + 7) / 8, 256, 0, stream>>>((const u16x8*)y16, (const float4*)x,
                                             offs, counts, (const unsigned*)stage,
                                             (u16x8*)io16);
    k_gemm<<<(NN + 63) / 64, 256, 0, stream>>>(io16, wfrag, b, out);
}

// Round 21
// 136.631 us; speedup vs baseline: 1.6492x; 1.0140x over previous
//
#include <hip/hip_runtime.h>

// CGCConv: out = (scatter_add(ew*pr[src]*x[src], dst) + x) @ W.T + b
// N=50000, E=800000, D=96, fp32.
//
// Session 2 / Round 21: RESUBMISSION of R18 (broker timeouts R18-R20).
// Ledger: F~69 fixed (268MB poison fill in-window + memset + gaps),
// sort 36.3, pull 25.2 (R16 16B gather, verified best 138.5), gemm ~8.
// Sort's BW floor ~5us => 7x gap; R5 halve-EPB was NEUTRAL => per-block
// fixed machinery dominates: (a) 4096 LDS atomics into ONE 256-bin table
// (16-way same-addr contention) (b) 16-barrier ladder scan.
// CHANGE (both sort kernels): per-wave histograms h[8][256] (8x less
// contention) + __shfl_up wave-scan (4 barriers instead of 16+).
// Edge order within node changes => fp32 sum-order noise only.
// pull/gemm untouched controls.
// Prediction: sort -> ~18-24, dur 138.5 -> ~121-127.
// Pipeline: memset(cur1) -> prep(bin) -> sortB(sort|cvt|Wfrag) -> pull -> gemm.

constexpr int NN = 50000;
constexpr int NE = 800000;
constexpr int DD = 96;
constexpr int NB = 196;                       // buckets: dst>>8 (256 nodes)
constexpr int CAPB = 4608;                    // mu=4082 + 8 sigma
constexpr int EPB = 4096;                     // edges per binA block
constexpr int NBLK = (NE + EPB - 1) / EPB;    // 196
constexpr int NCVT = (NN * DD / 4 + 511) / 512;  // 2344 cvt blocks

using s8v = __attribute__((ext_vector_type(8))) short;   // 8 bf16
using f4v = __attribute__((ext_vector_type(4))) float;   // 4 fp32
using u16x8 = __attribute__((ext_vector_type(8))) unsigned short;  // 16B

__device__ inline unsigned short f2bf(float f) {    // RNE fp32->bf16
    unsigned u = __float_as_uint(f);
    return (unsigned short)((u + 0x7FFFu + ((u >> 16) & 1u)) >> 16);
}
__device__ inline float bfh(unsigned short v) {
    return __uint_as_float((unsigned)v << 16);
}
__device__ inline unsigned long long pack_e(int meta, float c) {
    return (unsigned long long)(unsigned)meta |
           ((unsigned long long)(unsigned)__float_as_uint(c) << 32);
}

// Bin 4096 edges -> per-wave LDS histograms + shfl-scan counting-sort ->
// coalesced run writes. Entry u64 = {src:16 | dloc:8 | bucket:8 | coef:32}.
__global__ __launch_bounds__(512) void k_prep(const int* __restrict__ src,
                                              const int* __restrict__ dst,
                                              const float* __restrict__ ew,
                                              const float* __restrict__ pr,
                                              int* __restrict__ cur1,
                                              unsigned long long* __restrict__ stage) {
    int tid = threadIdx.x;
    int wv = tid >> 6, ln = tid & 63;
    __shared__ int h[8][256];                    // per-wave histograms, 8KB
    __shared__ int tot[256];                     // bin totals
    __shared__ int sc[256];                      // inclusive scan of tot
    __shared__ int gb[256];                      // global base per bucket
    __shared__ int wsum[4];                      // scan wave sums
    __shared__ unsigned long long sorted[EPB];   // 32 KB

    for (int i = ln; i < 256; i += 64) h[wv][i] = 0;  // own table: no barrier
    int base = blockIdx.x * EPB;
    int n = min(EPB, NE - base);

    unsigned long long ent[8]; int bkt[8]; int lrk[8];
    #pragma unroll
    for (int j = 0; j < 8; j++) {
        int e = base + j * 512 + tid;
        bkt[j] = -1;
        if (e < NE) {
            int d = dst[e];
            int s = src[e];
            float c = ew[e] * pr[s];
            int bk = d >> 8;
            bkt[j] = bk;
            lrk[j] = atomicAdd(&h[wv][bk], 1);   // own-wave table: 8x less contention
            ent[j] = pack_e(s | ((d & 255) << 16) | (bk << 24), c);
        }
    }
    __syncthreads();                             // B1: histograms complete
    int scv = 0;
    if (tid < 256) {
        int run = 0;                             // cross-wave prefix, in-place
        #pragma unroll
        for (int w = 0; w < 8; w++) { int v = h[w][tid]; h[w][tid] = run; run += v; }
        tot[tid] = run;
        scv = run;                               // wave-intrinsic inclusive scan
        #pragma unroll
        for (int o = 1; o < 64; o <<= 1) {
            int t = __shfl_up(scv, o);
            if (ln >= o) scv += t;
        }
        if (ln == 63) wsum[wv] = scv;
    }
    __syncthreads();                             // B2: wsum ready
    if (tid < 256) {
        int add = 0;
        #pragma unroll
        for (int w = 0; w < 4; w++) add += (w < wv) ? wsum[w] : 0;
        sc[tid] = scv + add;
    }
    if (tid < NB)
        gb[tid] = tot[tid] ? atomicAdd(&cur1[tid], tot[tid]) : 0;
    __syncthreads();                             // B3: sc/gb ready
    #pragma unroll
    for (int j = 0; j < 8; j++)
        if (bkt[j] >= 0)
            sorted[sc[bkt[j]] - tot[bkt[j]] + h[wv][bkt[j]] + lrk[j]] = ent[j];
    __syncthreads();                             // B4: sorted ready
    for (int i = tid; i < n; i += 512) {         // coalesced run writes
        unsigned long long e = sorted[i];
        int bk = ((int)(e >> 24)) & 0xff;
        stage[(size_t)bk * CAPB + gb[bk] + (i - (sc[bk] - tot[bk]))] = e;
    }
}

// Blocks [0,NB): per-bucket counting sort by dloc (per-wave hist + shfl
// scan); emits u32 {src | coef_bf16<<16} into first half of own region.
// Blocks [NB, NB+NCVT): y16 = bf16(x) streaming cvt.
// Block NB+NCVT: W -> bf16 pre-swizzled MFMA fragments (for k_gemm).
__global__ __launch_bounds__(512) void k_sortB(unsigned long long* __restrict__ stage,
                                               const int* __restrict__ cur1,
                                               int* __restrict__ offs,
                                               int* __restrict__ counts,
                                               const float4* __restrict__ x4,
                                               ushort4* __restrict__ y16v,
                                               const float* __restrict__ W,
                                               unsigned short* __restrict__ wfrag) {
    int tid = threadIdx.x;
    int blk = blockIdx.x;
    if (blk >= NB) {
        int ci = blk - NB;
        if (ci < NCVT) {                        // cvt phase
            int i = ci * 512 + tid;
            if (i < NN * DD / 4) {
                float4 v = x4[i];
                y16v[i] = make_ushort4(f2bf(v.x), f2bf(v.y), f2bf(v.z), f2bf(v.w));
            }
        } else {                                // W fragment phase (1 block)
            for (int i = tid; i < 18 * 512; i += 512) {
                int f = i >> 9, r = i & 511;
                int lane = r >> 3, j = r & 7;
                int ks = f / 6, nt = f - 6 * ks;
                int n = nt * 16 + (lane & 15);
                int k = ks * 32 + (lane >> 4) * 8 + j;
                wfrag[i] = f2bf(W[n * DD + k]);
            }
        }
        return;
    }
    int wv = tid >> 6, ln = tid & 63;
    __shared__ int h[8][256];                    // per-wave histograms, 8KB
    __shared__ int tot[256];
    __shared__ int sc[256];
    __shared__ int wsum[4];
    __shared__ unsigned sorted[CAPB];            // u32, 18.4 KB
    size_t base = (size_t)blk * CAPB;
    int n = cur1[blk];

    for (int i = ln; i < 256; i += 64) h[wv][i] = 0;  // own table: no barrier

    unsigned e32[9]; int dl[9]; int lrk[9];
    int m = 0;
    for (int i = tid; i < n; i += 512) {
        unsigned long long e = stage[base + i];
        int dloc = ((int)(e >> 16)) & 0xff;
        unsigned cb = (unsigned)(e >> 32);       // coef fp32 bits
        unsigned cbf = (cb + 0x7FFFu + ((cb >> 16) & 1u)) >> 16;  // bf16
        e32[m] = ((unsigned)e & 0xffffu) | (cbf << 16);
        dl[m] = dloc;
        lrk[m] = atomicAdd(&h[wv][dloc], 1);
        m++;
    }
    __syncthreads();                             // B1
    int scv = 0;
    if (tid < 256) {
        int run = 0;
        #pragma unroll
        for (int w = 0; w < 8; w++) { int v = h[w][tid]; h[w][tid] = run; run += v; }
        tot[tid] = run;
        scv = run;
        #pragma unroll
        for (int o = 1; o < 64; o <<= 1) {
            int t = __shfl_up(scv, o);
            if (ln >= o) scv += t;
        }
        if (ln == 63) wsum[wv] = scv;
    }
    __syncthreads();                             // B2
    if (tid < 256) {
        int add = 0;
        #pragma unroll
        for (int w = 0; w < 4; w++) add += (w < wv) ? wsum[w] : 0;
        sc[tid] = scv + add;
    }
    __syncthreads();                             // B3
    m = 0;
    for (int i = tid; i < n; i += 512) {
        int d = dl[m];
        sorted[sc[d] - tot[d] + h[wv][d] + lrk[m]] = e32[m];
        m++;
    }
    __syncthreads();                             // B4
    unsigned* outp = (unsigned*)(stage + base);  // first half of own region
    for (int i = tid; i < n; i += 512) outp[i] = sorted[i];
    if (tid < 256) {
        int d = (blk << 8) + tid;
        if (d < NN) {
            offs[d] = (int)(2 * base) + sc[tid] - tot[tid];   // u32 index
            counts[d] = tot[tid];
        }
    }
}

// Pull-aggregate (R16-verified): 8 nodes/block, lanes 0..11 own one ushort8
// (8 bf16 channels, 16B gather). Writes io16 = bf16(aggr + x). UNTOUCHED.
__global__ __launch_bounds__(256) void k_pull(const u16x8* __restrict__ y16v8,
                                              const float4* __restrict__ x4,
                                              const int* __restrict__ offs,
                                              const int* __restrict__ counts,
                                              const unsigned* __restrict__ ep,
                                              u16x8* __restrict__ io16v8) {
    int g = blockIdx.x * 8 + (threadIdx.x >> 5);
    int lane = threadIdx.x & 31;
    if (g >= NN || lane >= 12) return;
    int beg = offs[g];
    int deg = counts[g];
    float a0 = 0.f, a1 = 0.f, a2 = 0.f, a3 = 0.f;
    float a4 = 0.f, a5 = 0.f, a6 = 0.f, a7 = 0.f;
    int k = 0;
    for (; k + 8 <= deg; k += 8) {
        unsigned e[8];
        #pragma unroll
        for (int j = 0; j < 8; j++) e[j] = ep[beg + k + j];
        u16x8 u[8];
        #pragma unroll
        for (int j = 0; j < 8; j++)
            u[j] = y16v8[(size_t)(e[j] & 0xffff) * 12 + lane];
        #pragma unroll
        for (int j = 0; j < 8; j++) {
            float c = bfh((unsigned short)(e[j] >> 16));
            a0 += c * bfh(u[j][0]); a1 += c * bfh(u[j][1]);
            a2 += c * bfh(u[j][2]); a3 += c * bfh(u[j][3]);
            a4 += c * bfh(u[j][4]); a5 += c * bfh(u[j][5]);
            a6 += c * bfh(u[j][6]); a7 += c * bfh(u[j][7]);
        }
    }
    for (; k + 4 <= deg; k += 4) {
        unsigned e[4];
        #pragma unroll
        for (int j = 0; j < 4; j++) e[j] = ep[beg + k + j];
        u16x8 u[4];
        #pragma unroll
        for (int j = 0; j < 4; j++)
            u[j] = y16v8[(size_t)(e[j] & 0xffff) * 12 + lane];
        #pragma unroll
        for (int j = 0; j < 4; j++) {
            float c = bfh((unsigned short)(e[j] >> 16));
            a0 += c * bfh(u[j][0]); a1 += c * bfh(u[j][1]);
            a2 += c * bfh(u[j][2]); a3 += c * bfh(u[j][3]);
            a4 += c * bfh(u[j][4]); a5 += c * bfh(u[j][5]);
            a6 += c * bfh(u[j][6]); a7 += c * bfh(u[j][7]);
        }
    }
    for (; k < deg; k++) {
        unsigned e = ep[beg + k];
        u16x8 u = y16v8[(size_t)(e & 0xffff) * 12 + lane];
        float c = bfh((unsigned short)(e >> 16));
        a0 += c * bfh(u[0]); a1 += c * bfh(u[1]);
        a2 += c * bfh(u[2]); a3 += c * bfh(u[3]);
        a4 += c * bfh(u[4]); a5 += c * bfh(u[5]);
        a6 += c * bfh(u[6]); a7 += c * bfh(u[7]);
    }
    float4 xl = x4[(size_t)g * 24 + lane * 2];
    float4 xh = x4[(size_t)g * 24 + lane * 2 + 1];
    u16x8 o;
    o[0] = f2bf(a0 + xl.x); o[1] = f2bf(a1 + xl.y);
    o[2] = f2bf(a2 + xl.z); o[3] = f2bf(a3 + xl.w);
    o[4] = f2bf(a4 + xh.x); o[5] = f2bf(a5 + xh.y);
    o[6] = f2bf(a6 + xh.z); o[7] = f2bf(a7 + xh.w);
    io16v8[(size_t)g * 12 + lane] = o;
}

// MFMA GEMM: out[r,o] = sum_d io16[r,d]*W[o,d] + b[o], fp32 out.
// B-frags pre-swizzled in ws (wfrag), loaded coalesced 16B/lane from L2.
// C/D: col=lane&15, row=quad*4+reg (HW-verified; absmax-confirmed).
__global__ __launch_bounds__(256) void k_gemm(const unsigned short* __restrict__ io16,
                                              const unsigned short* __restrict__ wfrag,
                                              const float* __restrict__ b,
                                              float* __restrict__ out) {
    int tid = threadIdx.x;
    int wave = tid >> 6, lane = tid & 63;
    int quad = lane >> 4, m16 = lane & 15;
    int r0 = blockIdx.x * 64 + wave * 16;
    int rowa = r0 + m16;
    if (rowa >= NN) rowa = NN - 1;           // clamped A read, store masked

    const s8v* wf = (const s8v*)wfrag;       // frag (ks*6+nt) x 64 lanes

    f4v acc[6];
    #pragma unroll
    for (int nt = 0; nt < 6; nt++) acc[nt] = (f4v){0.f, 0.f, 0.f, 0.f};

    #pragma unroll
    for (int ks = 0; ks < 3; ks++) {
        s8v a = *(const s8v*)(io16 + (size_t)rowa * DD + ks * 32 + quad * 8);
        #pragma unroll
        for (int nt = 0; nt < 6; nt++) {
            s8v bb = wf[(ks * 6 + nt) * 64 + lane];
            acc[nt] = __builtin_amdgcn_mfma_f32_16x16x32_bf16(a, bb, acc[nt], 0, 0, 0);
        }
    }

    #pragma unroll
    for (int nt = 0; nt < 6; nt++) {
        float bias = b[nt * 16 + m16];
        #pragma unroll
        for (int reg = 0; reg < 4; reg++) {
            int rr = r0 + quad * 4 + reg;
            if (rr < NN)
                out[(size_t)rr * DD + nt * 16 + m16] = acc[nt][reg] + bias;
        }
    }
}

extern "C" void kernel_launch(void* const* d_in, const int* in_sizes, int n_in,
                              void* d_out, int out_size, void* d_ws, size_t ws_size,
                              hipStream_t stream) {
    const float* x  = (const float*)d_in[0];
    const int*   ei = (const int*)d_in[1];   // [2,E]: [0..E)=src, [E..2E)=dst
    const float* ew = (const float*)d_in[2];
    const float* pr = (const float*)d_in[3];
    const float* W  = (const float*)d_in[4];
    const float* b  = (const float*)d_in[5];
    float* out = (float*)d_out;

    // ws layout (~26.9 MB)
    unsigned long long* stage = (unsigned long long*)d_ws;       // NB*CAPB u64
    unsigned short* y16 = (unsigned short*)(stage + (size_t)NB * CAPB);  // 9.6MB
    int* cur1   = (int*)(y16 + (size_t)NN * DD);      // 196
    int* offs   = cur1 + NB;                          // 50000
    int* counts = offs + NN;                          // 50000
    unsigned short* io16 = (unsigned short*)(counts + NN);       // 9.6MB
    unsigned short* wfrag = io16 + (size_t)NN * DD;   // 18*512 bf16 = 18.4KB

    const int* src = ei;
    const int* dst = ei + NE;

    hipMemsetAsync(cur1, 0, NB * sizeof(int), stream);
    k_prep<<<NBLK, 512, 0, stream>>>(src, dst, ew, pr, cur1, stage);
    k_sortB<<<NB + NCVT + 1, 512, 0, stream>>>(stage, cur1, offs, counts,
                                               (const float4*)x, (ushort4*)y16,
                                               W, wfrag);
    k_pull<<<(NN + 7) / 8, 256, 0, stream>>>((const u16x8*)y16, (const float4*)x,
                                             offs, counts, (const unsigned*)stage,
                                             (u16x8*)io16);
    k_gemm<<<(NN + 63) / 64, 256, 0, stream>>>(io16, wfrag, b, out);
}